// Round 22
// baseline (320.218 us; speedup 1.0000x reference)
//
#include <hip/hip_runtime.h>
#include <hip/hip_bf16.h>
#include <type_traits>

#define N_NODES 100000
#define N_EDGES 1600000
#define SLICE_N 12500   // N_NODES / 8 dst-slices for XCD-local fill
#define CAP     64      // bucket capacity (Poisson(16) max deg ~45)

typedef float f32x4 __attribute__((ext_vector_type(4)));
typedef _Float16 f16x8 __attribute__((ext_vector_type(8)));

// ---------------- all three W[K][M] -> Wt[M][K] fp16 in one launch ----------------
__global__ void wconv_all_kernel(const float* __restrict__ W0, const float* __restrict__ W1,
                                 const float* __restrict__ W2, _Float16* __restrict__ Wt0,
                                 _Float16* __restrict__ Wt1, _Float16* __restrict__ Wt2) {
    int i = blockIdx.x * 256 + threadIdx.x;
    if (i < 32768) {                   // W0: 256x128
        int k = i / 128, col = i % 128;
        Wt0[col * 256 + k] = (_Float16)W0[i];
    } else if (i < 49152) {            // W1: 128x128
        int j = i - 32768;
        int k = j / 128, col = j % 128;
        Wt1[col * 128 + k] = (_Float16)W1[j];
    } else if (i < 53248) {            // W2: 128x32
        int j = i - 49152;
        int k = j / 32, col = j % 32;
        Wt2[col * 128 + k] = (_Float16)W2[j];
    }
}

__global__ void dinv_kernel(const int* __restrict__ cnt, float* __restrict__ dinv) {
    int i = blockIdx.x * 256 + threadIdx.x;
    if (i < N_NODES) dinv[i] = 1.0f / sqrtf((float)cnt[i] + 1.0f);
}

// ---------------- LDS-free fp16 MFMA GEMM tile body, FR=2, A 3-deep / B 2-deep ----------------
// C[r,:] = fp16( (A @ W)[r,:] )  (unscaled)
#define LOADA(st, k0)                                                          \
    do {                                                                       \
        _Pragma("unroll")                                                      \
        for (int r = 0; r < 2; ++r) {                                          \
            const float* ap = A + (size_t)gr[r] * K + (k0) + kof;              \
            a32[st][r][0] = *(const f32x4*)ap;                                 \
            a32[st][r][1] = *(const f32x4*)(ap + 4);                           \
        }                                                                      \
    } while (0)

#define LOADB(st, k0)                                                          \
    do {                                                                       \
        _Pragma("unroll")                                                      \
        for (int c = 0; c < FC; ++c)                                           \
            bst[st][c] = *(const f16x8*)(Bt + (size_t)(c * 16 + l15) * K + (k0) + kof); \
    } while (0)

template<int K, int M>
__device__ __forceinline__ void gemm_tile_body(const float* __restrict__ A,
                                               const _Float16* __restrict__ Bt,
                                               _Float16* __restrict__ C,
                                               int blk, int tid) {
    constexpr int FC = M / 16;
    constexpr int NIT = K / 32;
    const int wave = tid >> 6, lane = tid & 63;
    const int row0 = blk * 128;
    const int r0 = wave * 32;
    const int l15 = lane & 15, kof = (lane >> 4) * 8;

    f32x4 acc[2][FC] = {};
    int gr[2];
    #pragma unroll
    for (int r = 0; r < 2; ++r) {
        int g = row0 + r0 + r * 16 + l15;
        gr[r] = (g < N_NODES) ? g : N_NODES - 1;
    }

    f32x4 a32[3][2][2];
    f16x8 bst[2][FC];

    LOADA(0, 0);
    if (NIT > 1) LOADA(1, 32);
    LOADB(0, 0);

    #pragma unroll
    for (int it = 0; it < NIT; ++it) {
        if (it + 2 < NIT) LOADA((it + 2) % 3, (it + 2) * 32);
        if (it + 1 < NIT) LOADB((it + 1) % 2, (it + 1) * 32);
        f16x8 af[2];
        #pragma unroll
        for (int r = 0; r < 2; ++r) {
            #pragma unroll
            for (int j = 0; j < 4; ++j) {
                af[r][j] = (_Float16)a32[it % 3][r][0][j];
                af[r][4 + j] = (_Float16)a32[it % 3][r][1][j];
            }
        }
        #pragma unroll
        for (int c = 0; c < FC; ++c)
            #pragma unroll
            for (int r = 0; r < 2; ++r)
                acc[r][c] = __builtin_amdgcn_mfma_f32_16x16x32_f16(af[r], bst[it % 2][c], acc[r][c], 0, 0, 0);
    }

    // epilogue: C/D frag layout col=lane&15, row=(lane>>4)*4+reg; fp16 store
    #pragma unroll
    for (int r = 0; r < 2; ++r) {
        #pragma unroll
        for (int j = 0; j < 4; ++j) {
            int g = row0 + r0 + r * 16 + (lane >> 4) * 4 + j;
            if (g >= N_NODES) continue;
            #pragma unroll
            for (int c = 0; c < FC; ++c)
                C[(size_t)g * M + c * 16 + l15] = (_Float16)acc[r][c][j];
        }
    }
}

// ---- fused: bucket CSR fill (6256 blocks) || unscaled gemm0 (782 blocks) ----
// b%9==0 -> gemm tile b/9. Others: slice = b&7 (XCD-pinned; 8 consecutive non-gemm
// b's span 9 ints -> all 8 residues exactly once), chunk = fill-ordinal >> 3.
__global__ __launch_bounds__(256) void fused_fill_gemm0(const int* __restrict__ esrc,
                                                        const int* __restrict__ edst,
                                                        int* __restrict__ cnt,
                                                        int* __restrict__ esorted,
                                                        const float* __restrict__ x,
                                                        const _Float16* __restrict__ Wt0,
                                                        _Float16* __restrict__ h) {
    const int b = blockIdx.x;
    const int g = b / 9;
    if (b % 9 == 0) {
        gemm_tile_body<256, 128>(x, Wt0, h, g, threadIdx.x);
        return;
    }
    const int f = b - g - 1;          // fill ordinal 0..6255
    const int slice = b & 7;          // XCD-aligned slice
    const int chunk = f >> 3;         // 0..781
    const int base = chunk * 2048 + threadIdx.x;
    const int lo = slice * SLICE_N, hi = lo + SLICE_N;
    #pragma unroll
    for (int i = 0; i < 8; ++i) {
        int e = base + i * 256;
        if (e < N_EDGES) {
            int d = edst[e];
            if (d >= lo && d < hi) {
                int pos = atomicAdd(&cnt[d], 1);
                if (pos < CAP) esorted[(size_t)d * CAP + pos] = esrc[e];
            }
        }
    }
}

// ---- fused bucket-gather + GEMM (uniform unscaled-h convention):
//      act = dinv[n]*( sum_src dinv[src]*h[src] + dinv[n]*h[n] ) + bias
//      outh[n,:] = fp16( act @ W )   (unscaled)
// Block = 16 nodes x 16 lanes; act tile in LDS (4.4 KB only); W read from global (L2).
template<int OUTC>
__global__ __launch_bounds__(256) void gather_gemm_kernel(const int* __restrict__ cnt,
                                                          const int* __restrict__ esorted,
                                                          const float* __restrict__ dinv,
                                                          const f16x8* __restrict__ hs,
                                                          const float* __restrict__ bias,
                                                          const _Float16* __restrict__ Wt,
                                                          _Float16* __restrict__ outh) {
    __shared__ _Float16 As[16][136];     // 16 act rows, +8 pad
    const int tid = threadIdx.x;
    const int n16 = tid >> 4;
    const int lane = tid & 15;
    const int node = blockIdx.x * 16 + n16;
    {
        int len = cnt[node]; if (len > CAP) len = CAP;
        const int* __restrict__ lst = esorted + (size_t)node * CAP;
        float dn = dinv[node];
        f16x8 hv = hs[(size_t)node * 16 + lane];   // self term (unscaled h)
        float acc[8];
        #pragma unroll
        for (int d = 0; d < 8; ++d) acc[d] = dn * (float)hv[d];
        int j = 0;
        for (; j + 8 <= len; j += 8) {
            int s[8];
            float ds_[8];
            f16x8 v[8];
            #pragma unroll
            for (int k = 0; k < 8; ++k) s[k] = lst[j + k];
            #pragma unroll
            for (int k = 0; k < 8; ++k) { ds_[k] = dinv[s[k]]; v[k] = hs[(size_t)s[k] * 16 + lane]; }
            #pragma unroll
            for (int k = 0; k < 8; ++k)
                #pragma unroll
                for (int d = 0; d < 8; ++d) acc[d] = fmaf(ds_[k], (float)v[k][d], acc[d]);
        }
        for (; j < len; ++j) {
            int s = lst[j];
            float ds_ = dinv[s];
            f16x8 v = hs[(size_t)s * 16 + lane];
            #pragma unroll
            for (int d = 0; d < 8; ++d) acc[d] = fmaf(ds_, (float)v[d], acc[d]);
        }
        const float* bp = bias + lane * 8;
        f16x8 o;
        #pragma unroll
        for (int d = 0; d < 8; ++d) o[d] = (_Float16)(acc[d] * dn + bp[d]);
        *(f16x8*)&As[n16][lane * 8] = o;
    }
    __syncthreads();

    // ---- MFMA phase: 16 rows x OUTC cols, K=128; W fragments straight from global ----
    const int wave = tid >> 6, l64 = tid & 63;
    const int l15 = l64 & 15, kq = l64 >> 4;
    constexpr int NF = OUTC / 16;
    constexpr int FPW = (NF + 3) / 4;   // frags per wave (2 for 128, 1 for 32)
    #pragma unroll
    for (int f = 0; f < FPW; ++f) {
        int cf = wave * FPW + f;
        if (cf < NF) {
            int col = cf * 16 + l15;
            f32x4 a2 = {};
            #pragma unroll
            for (int it = 0; it < 4; ++it) {
                f16x8 af = *(const f16x8*)&As[l15][it * 32 + kq * 8];
                f16x8 bf = *(const f16x8*)(Wt + (size_t)col * 128 + it * 32 + kq * 8);
                a2 = __builtin_amdgcn_mfma_f32_16x16x32_f16(af, bf, a2, 0, 0, 0);
            }
            #pragma unroll
            for (int j = 0; j < 4; ++j) {
                int g = blockIdx.x * 16 + kq * 4 + j;
                outh[(size_t)g * OUTC + col] = (_Float16)a2[j];
            }
        }
    }
}

// ---------------- layer-2 gather (unscaled h2) fused with log_softmax, fp32 out ----------------
__global__ __launch_bounds__(256) void gather_lsm_kernel(const int* __restrict__ cnt,
                                                         const int* __restrict__ esorted,
                                                         const float* __restrict__ dinv,
                                                         const f16x8* __restrict__ hs,
                                                         const float* __restrict__ bias,
                                                         float* __restrict__ out) {
    constexpr int R = 4;   // f16x8 chunks per 32-wide row
    int gid = blockIdx.x * blockDim.x + threadIdx.x;
    int node = gid / 4;
    int lane = gid % 4;
    if (node >= N_NODES) return;
    int len = cnt[node]; if (len > CAP) len = CAP;
    const int* __restrict__ lst = esorted + (size_t)node * CAP;
    float dn = dinv[node];
    f16x8 hv = hs[(size_t)node * R + lane];
    float acc[8];
    #pragma unroll
    for (int d = 0; d < 8; ++d) acc[d] = dn * (float)hv[d];
    int j = 0;
    for (; j + 8 <= len; j += 8) {
        int s[8];
        float ds_[8];
        f16x8 v[8];
        #pragma unroll
        for (int k = 0; k < 8; ++k) s[k] = lst[j + k];
        #pragma unroll
        for (int k = 0; k < 8; ++k) { ds_[k] = dinv[s[k]]; v[k] = hs[(size_t)s[k] * R + lane]; }
        #pragma unroll
        for (int k = 0; k < 8; ++k)
            #pragma unroll
            for (int d = 0; d < 8; ++d) acc[d] = fmaf(ds_[k], (float)v[k][d], acc[d]);
    }
    for (; j < len; ++j) {
        int s = lst[j];
        float ds_ = dinv[s];
        f16x8 v = hs[(size_t)s * R + lane];
        #pragma unroll
        for (int d = 0; d < 8; ++d) acc[d] = fmaf(ds_, (float)v[d], acc[d]);
    }
    const float* bp = bias + lane * 8;
    float o[8];
    #pragma unroll
    for (int d = 0; d < 8; ++d) o[d] = acc[d] * dn + bp[d];
    // log_softmax over the 32-class row (4 lanes x 8)
    float m = o[0];
    #pragma unroll
    for (int d = 1; d < 8; ++d) m = fmaxf(m, o[d]);
    m = fmaxf(m, __shfl_xor(m, 1, 4));
    m = fmaxf(m, __shfl_xor(m, 2, 4));
    float s = 0.f;
    #pragma unroll
    for (int d = 0; d < 8; ++d) s += expf(o[d] - m);
    s += __shfl_xor(s, 1, 4);
    s += __shfl_xor(s, 2, 4);
    float ls = m + logf(s);
    f32x4 r0, r1;
    #pragma unroll
    for (int d = 0; d < 4; ++d) { r0[d] = o[d] - ls; r1[d] = o[4 + d] - ls; }
    f32x4* op = (f32x4*)out + (size_t)node * 8 + lane * 2;
    op[0] = r0;
    op[1] = r1;
}

extern "C" void kernel_launch(void* const* d_in, const int* in_sizes, int n_in,
                              void* d_out, int out_size, void* d_ws, size_t ws_size,
                              hipStream_t stream) {
    const float* x  = (const float*)d_in[0];
    const int*   ei = (const int*)d_in[1];     // [2, E] int32
    const float* W0 = (const float*)d_in[2];
    const float* b0 = (const float*)d_in[3];
    const float* W1 = (const float*)d_in[4];
    const float* b1 = (const float*)d_in[5];
    const float* W2 = (const float*)d_in[6];
    const float* b2 = (const float*)d_in[7];
    float* out = (float*)d_out;

    char* ws = (char*)d_ws;
    float* dinv    = (float*)(ws + 0);                      // 400 KB
    int*   cnt     = (int*)  (ws + (512 << 10));            // 400 KB (degree + cursor)
    int*   esorted = (int*)  (ws + (1 << 20));              // 25.6 MB (bucketed, CAP=64)
    _Float16* Wt0  = (_Float16*)(ws + 27262976);            // 64 KB
    _Float16* Wt1  = (_Float16*)(ws + 27262976 + 65536);    // 32 KB
    _Float16* Wt2  = (_Float16*)(ws + 27262976 + 98304);    // 8 KB
    _Float16* h0   = (_Float16*)(ws + 28311552);            // 25.6 MB (layer0 h, unscaled)
    _Float16* h1   = (_Float16*)(ws + 28311552 + 26214400); // 25.6 MB (layer1 h, unscaled)
    _Float16* h2   = (_Float16*)(ws + 28311552 + 52428800); // 6.4 MB (layer2 h, unscaled)
    const int* esrc = ei;
    const int* edst = ei + N_EDGES;

    const int NB = (N_NODES + 255) / 256;   // 391

    // ---- W convert, then fused [bucket-CSR fill || unscaled gemm0], then dinv ----
    (void)hipMemsetAsync(cnt, 0, N_NODES * sizeof(int), stream);
    wconv_all_kernel<<<208, 256, 0, stream>>>(W0, W1, W2, Wt0, Wt1, Wt2);
    fused_fill_gemm0<<<782 * 9, 256, 0, stream>>>(esrc, edst, cnt, esorted, x, Wt0, h0);
    dinv_kernel<<<NB, 256, 0, stream>>>(cnt, dinv);

    // ---- layer 0 aggregate + layer 1 GEMM (fused) -> h1 ----
    gather_gemm_kernel<128><<<N_NODES / 16, 256, 0, stream>>>(
        cnt, esorted, dinv, (const f16x8*)h0, b0, Wt1, h1);

    // ---- layer 1 aggregate + layer 2 GEMM (fused) -> h2 ----
    gather_gemm_kernel<32><<<N_NODES / 16, 256, 0, stream>>>(
        cnt, esorted, dinv, (const f16x8*)h1, b1, Wt2, h2);

    // ---- layer 2 aggregate fused with log_softmax, writes d_out ----
    gather_lsm_kernel<<<(N_NODES * 4 + 255) / 256, 256, 0, stream>>>(
        cnt, esorted, dinv, (const f16x8*)h2, b2, out);
}

// Round 23
// 309.781 us; speedup vs baseline: 1.0337x; 1.0337x over previous
//
#include <hip/hip_runtime.h>
#include <hip/hip_bf16.h>
#include <type_traits>

#define N_NODES 100000
#define N_EDGES 1600000
#define SLICE_N 12500   // N_NODES / 8 dst-slices for XCD-local fill
#define CAP     64      // bucket capacity (Poisson(16) max deg ~45)

typedef float f32x4 __attribute__((ext_vector_type(4)));
typedef _Float16 f16x8 __attribute__((ext_vector_type(8)));

// ---------------- all three W[K][M] -> Wt[M][K] fp16 in one launch ----------------
__global__ void wconv_all_kernel(const float* __restrict__ W0, const float* __restrict__ W1,
                                 const float* __restrict__ W2, _Float16* __restrict__ Wt0,
                                 _Float16* __restrict__ Wt1, _Float16* __restrict__ Wt2) {
    int i = blockIdx.x * 256 + threadIdx.x;
    if (i < 32768) {                   // W0: 256x128
        int k = i / 128, col = i % 128;
        Wt0[col * 256 + k] = (_Float16)W0[i];
    } else if (i < 49152) {            // W1: 128x128
        int j = i - 32768;
        int k = j / 128, col = j % 128;
        Wt1[col * 128 + k] = (_Float16)W1[j];
    } else if (i < 53248) {            // W2: 128x32
        int j = i - 49152;
        int k = j / 32, col = j % 32;
        Wt2[col * 128 + k] = (_Float16)W2[j];
    }
}

// ---------------- LDS-free fp16 MFMA GEMM tile body, FR=2, A 3-deep / B 2-deep ----------------
#define LOADA(st, k0)                                                          \
    do {                                                                       \
        _Pragma("unroll")                                                      \
        for (int r = 0; r < 2; ++r) {                                          \
            const float* ap = A + (size_t)gr[r] * K + (k0) + kof;              \
            a32[st][r][0] = *(const f32x4*)ap;                                 \
            a32[st][r][1] = *(const f32x4*)(ap + 4);                           \
        }                                                                      \
    } while (0)

#define LOADB(st, k0)                                                          \
    do {                                                                       \
        _Pragma("unroll")                                                      \
        for (int c = 0; c < FC; ++c)                                           \
            bst[st][c] = *(const f16x8*)(Bt + (size_t)(c * 16 + l15) * K + (k0) + kof); \
    } while (0)

// C[r,:] = fp16( (A @ W)[r,:] )  (unscaled; scaling applied by scale_dinv later)
template<int K, int M>
__device__ __forceinline__ void gemm_tile_body(const float* __restrict__ A,
                                               const _Float16* __restrict__ Bt,
                                               _Float16* __restrict__ C,
                                               int blk, int tid) {
    constexpr int FC = M / 16;
    constexpr int NIT = K / 32;
    const int wave = tid >> 6, lane = tid & 63;
    const int row0 = blk * 128;
    const int r0 = wave * 32;
    const int l15 = lane & 15, kof = (lane >> 4) * 8;

    f32x4 acc[2][FC] = {};
    int gr[2];
    #pragma unroll
    for (int r = 0; r < 2; ++r) {
        int g = row0 + r0 + r * 16 + l15;
        gr[r] = (g < N_NODES) ? g : N_NODES - 1;
    }

    f32x4 a32[3][2][2];
    f16x8 bst[2][FC];

    LOADA(0, 0);
    if (NIT > 1) LOADA(1, 32);
    LOADB(0, 0);

    #pragma unroll
    for (int it = 0; it < NIT; ++it) {
        if (it + 2 < NIT) LOADA((it + 2) % 3, (it + 2) * 32);
        if (it + 1 < NIT) LOADB((it + 1) % 2, (it + 1) * 32);
        f16x8 af[2];
        #pragma unroll
        for (int r = 0; r < 2; ++r) {
            #pragma unroll
            for (int j = 0; j < 4; ++j) {
                af[r][j] = (_Float16)a32[it % 3][r][0][j];
                af[r][4 + j] = (_Float16)a32[it % 3][r][1][j];
            }
        }
        #pragma unroll
        for (int c = 0; c < FC; ++c)
            #pragma unroll
            for (int r = 0; r < 2; ++r)
                acc[r][c] = __builtin_amdgcn_mfma_f32_16x16x32_f16(af[r], bst[it % 2][c], acc[r][c], 0, 0, 0);
    }

    // epilogue: C/D frag layout col=lane&15, row=(lane>>4)*4+reg; fp16 store
    #pragma unroll
    for (int r = 0; r < 2; ++r) {
        #pragma unroll
        for (int j = 0; j < 4; ++j) {
            int g = row0 + r0 + r * 16 + (lane >> 4) * 4 + j;
            if (g >= N_NODES) continue;
            #pragma unroll
            for (int c = 0; c < FC; ++c)
                C[(size_t)g * M + c * 16 + l15] = (_Float16)acc[r][c][j];
        }
    }
}

// ---- fused: bucket CSR fill (6256 blocks) || unscaled gemm0 (782 blocks) ----
__global__ __launch_bounds__(256) void fused_fill_gemm0(const int* __restrict__ esrc,
                                                        const int* __restrict__ edst,
                                                        int* __restrict__ cnt,
                                                        int* __restrict__ esorted,
                                                        const float* __restrict__ x,
                                                        const _Float16* __restrict__ Wt0,
                                                        _Float16* __restrict__ h) {
    const int b = blockIdx.x;
    const int g = b / 9;
    if (b % 9 == 0) {
        gemm_tile_body<256, 128>(x, Wt0, h, g, threadIdx.x);
        return;
    }
    const int f = b - g - 1;          // fill ordinal 0..6255
    const int slice = b & 7;          // XCD-aligned slice
    const int chunk = f >> 3;         // 0..781
    const int base = chunk * 2048 + threadIdx.x;
    const int lo = slice * SLICE_N, hi = lo + SLICE_N;
    #pragma unroll
    for (int i = 0; i < 8; ++i) {
        int e = base + i * 256;
        if (e < N_EDGES) {
            int d = edst[e];
            if (d >= lo && d < hi) {
                int pos = atomicAdd(&cnt[d], 1);
                if (pos < CAP) esorted[(size_t)d * CAP + pos] = esrc[e];
            }
        }
    }
}

// ---- scale h by dinv (computed from cnt) and emit dinv: hs = h * dinv[row] ----
__global__ __launch_bounds__(256) void scale_dinv_kernel(const int* __restrict__ cnt,
                                                         float* __restrict__ dinv,
                                                         f16x8* __restrict__ hs) {
    int i = blockIdx.x * 256 + threadIdx.x;   // f16x8 chunk index, 16 per node
    if (i >= N_NODES * 16) return;
    int n = i >> 4;
    float dn = 1.0f / sqrtf((float)cnt[n] + 1.0f);
    if ((i & 15) == 0) dinv[n] = dn;
    f16x8 v = hs[i];
    #pragma unroll
    for (int d = 0; d < 8; ++d) v[d] = (_Float16)((float)v[d] * dn);
    hs[i] = v;
}

// ---- fused bucket-gather + GEMM: act = dinv[n]*(sum hs[src] + hs[n]) + bias,
//      outh[n,:] = fp16( (act @ W)[n,:] * dinv[n] ).
// Block = 16 nodes x 16 lanes; act tile in LDS (4.4 KB); W read from global (L2-resident).
template<int OUTC>
__global__ __launch_bounds__(256) void gather_gemm_kernel(const int* __restrict__ cnt,
                                                          const int* __restrict__ esorted,
                                                          const float* __restrict__ dinv,
                                                          const f16x8* __restrict__ hs,
                                                          const float* __restrict__ bias,
                                                          const _Float16* __restrict__ Wt,
                                                          _Float16* __restrict__ outh) {
    __shared__ _Float16 As[16][136];     // 16 act rows, +8 pad
    const int tid = threadIdx.x;

    // ---- gather phase: node = blk*16 + tid/16, lane = tid%16 owns 8 dims ----
    const int n16 = tid >> 4;
    const int lane = tid & 15;
    const int node = blockIdx.x * 16 + n16;
    {
        int len = cnt[node]; if (len > CAP) len = CAP;
        const int* __restrict__ lst = esorted + (size_t)node * CAP;
        float dn = dinv[node];
        f16x8 hv = hs[(size_t)node * 16 + lane];   // self term (pre-scaled hs)
        float acc[8];
        #pragma unroll
        for (int d = 0; d < 8; ++d) acc[d] = (float)hv[d];
        int j = 0;
        for (; j + 8 <= len; j += 8) {
            int s[8];
            f16x8 v[8];
            #pragma unroll
            for (int k = 0; k < 8; ++k) s[k] = lst[j + k];
            #pragma unroll
            for (int k = 0; k < 8; ++k) v[k] = hs[(size_t)s[k] * 16 + lane];
            #pragma unroll
            for (int k = 0; k < 8; ++k)
                #pragma unroll
                for (int d = 0; d < 8; ++d) acc[d] += (float)v[k][d];
        }
        for (; j < len; ++j) {
            f16x8 v = hs[(size_t)lst[j] * 16 + lane];
            #pragma unroll
            for (int d = 0; d < 8; ++d) acc[d] += (float)v[d];
        }
        const float* bp = bias + lane * 8;
        f16x8 o;
        #pragma unroll
        for (int d = 0; d < 8; ++d) o[d] = (_Float16)(acc[d] * dn + bp[d]);
        *(f16x8*)&As[n16][lane * 8] = o;
    }
    __syncthreads();

    // ---- MFMA phase: 16 rows x OUTC cols, K=128; W fragments straight from global ----
    const int wave = tid >> 6, l64 = tid & 63;
    const int l15 = l64 & 15, kq = l64 >> 4;
    constexpr int NF = OUTC / 16;
    constexpr int FPW = (NF + 3) / 4;   // frags per wave (2 for 128, 1 for 32)
    #pragma unroll
    for (int f = 0; f < FPW; ++f) {
        int cf = wave * FPW + f;
        if (cf < NF) {
            int col = cf * 16 + l15;
            f32x4 a2 = {};
            #pragma unroll
            for (int it = 0; it < 4; ++it) {
                f16x8 af = *(const f16x8*)&As[l15][it * 32 + kq * 8];
                f16x8 bf = *(const f16x8*)(Wt + (size_t)col * 128 + it * 32 + kq * 8);
                a2 = __builtin_amdgcn_mfma_f32_16x16x32_f16(af, bf, a2, 0, 0, 0);
            }
            #pragma unroll
            for (int j = 0; j < 4; ++j) {
                int g = blockIdx.x * 16 + kq * 4 + j;
                outh[(size_t)g * OUTC + col] = (_Float16)(a2[j] * dinv[g]);
            }
        }
    }
}

// ---------------- layer-2 bucket gather fused with log_softmax (M=32, G=4), fp32 out ----------------
__global__ __launch_bounds__(256) void gather_lsm_kernel(const int* __restrict__ cnt,
                                                         const int* __restrict__ esorted,
                                                         const float* __restrict__ dinv,
                                                         const f16x8* __restrict__ hs,
                                                         const float* __restrict__ bias,
                                                         float* __restrict__ out) {
    constexpr int R = 4;   // f16x8 chunks per 32-wide row
    int gid = blockIdx.x * blockDim.x + threadIdx.x;
    int node = gid / 4;
    int lane = gid % 4;
    if (node >= N_NODES) return;
    int len = cnt[node]; if (len > CAP) len = CAP;
    const int* __restrict__ lst = esorted + (size_t)node * CAP;
    float dn = dinv[node];
    f16x8 hv = hs[(size_t)node * R + lane];
    float acc[8];
    #pragma unroll
    for (int d = 0; d < 8; ++d) acc[d] = (float)hv[d];
    int j = 0;
    for (; j + 8 <= len; j += 8) {
        int s[8];
        f16x8 v[8];
        #pragma unroll
        for (int k = 0; k < 8; ++k) s[k] = lst[j + k];
        #pragma unroll
        for (int k = 0; k < 8; ++k) v[k] = hs[(size_t)s[k] * R + lane];
        #pragma unroll
        for (int k = 0; k < 8; ++k)
            #pragma unroll
            for (int d = 0; d < 8; ++d) acc[d] += (float)v[k][d];
    }
    for (; j < len; ++j) {
        f16x8 v = hs[(size_t)lst[j] * R + lane];
        #pragma unroll
        for (int d = 0; d < 8; ++d) acc[d] += (float)v[d];
    }
    const float* bp = bias + lane * 8;
    float o[8];
    #pragma unroll
    for (int d = 0; d < 8; ++d) o[d] = acc[d] * dn + bp[d];
    // log_softmax over the 32-class row (4 lanes x 8)
    float m = o[0];
    #pragma unroll
    for (int d = 1; d < 8; ++d) m = fmaxf(m, o[d]);
    m = fmaxf(m, __shfl_xor(m, 1, 4));
    m = fmaxf(m, __shfl_xor(m, 2, 4));
    float s = 0.f;
    #pragma unroll
    for (int d = 0; d < 8; ++d) s += expf(o[d] - m);
    s += __shfl_xor(s, 1, 4);
    s += __shfl_xor(s, 2, 4);
    float ls = m + logf(s);
    f32x4 r0, r1;
    #pragma unroll
    for (int d = 0; d < 4; ++d) { r0[d] = o[d] - ls; r1[d] = o[4 + d] - ls; }
    f32x4* op = (f32x4*)out + (size_t)node * 8 + lane * 2;
    op[0] = r0;
    op[1] = r1;
}

extern "C" void kernel_launch(void* const* d_in, const int* in_sizes, int n_in,
                              void* d_out, int out_size, void* d_ws, size_t ws_size,
                              hipStream_t stream) {
    const float* x  = (const float*)d_in[0];
    const int*   ei = (const int*)d_in[1];     // [2, E] int32
    const float* W0 = (const float*)d_in[2];
    const float* b0 = (const float*)d_in[3];
    const float* W1 = (const float*)d_in[4];
    const float* b1 = (const float*)d_in[5];
    const float* W2 = (const float*)d_in[6];
    const float* b2 = (const float*)d_in[7];
    float* out = (float*)d_out;

    char* ws = (char*)d_ws;
    float* dinv    = (float*)(ws + 0);                      // 400 KB
    int*   cnt     = (int*)  (ws + (512 << 10));            // 400 KB (degree + cursor)
    int*   esorted = (int*)  (ws + (1 << 20));              // 25.6 MB (bucketed, CAP=64)
    _Float16* Wt0  = (_Float16*)(ws + 27262976);            // 64 KB
    _Float16* Wt1  = (_Float16*)(ws + 27262976 + 65536);    // 32 KB
    _Float16* Wt2  = (_Float16*)(ws + 27262976 + 98304);    // 8 KB
    _Float16* hs   = (_Float16*)(ws + 28311552);            // 25.6 MB (layer0 h / h*dinv)
    _Float16* hs1  = (_Float16*)(ws + 28311552 + 26214400); // 25.6 MB (layer1 h*dinv)
    _Float16* hs2  = (_Float16*)(ws + 28311552 + 52428800); // 6.4 MB (layer2 h*dinv)
    const int* esrc = ei;
    const int* edst = ei + N_EDGES;

    // ---- W convert, then fused [bucket-CSR fill || unscaled gemm0] ----
    (void)hipMemsetAsync(cnt, 0, N_NODES * sizeof(int), stream);
    wconv_all_kernel<<<208, 256, 0, stream>>>(W0, W1, W2, Wt0, Wt1, Wt2);
    fused_fill_gemm0<<<782 * 9, 256, 0, stream>>>(esrc, edst, cnt, esorted, x, Wt0, hs);
    // dinv = rsqrt(deg+1); hs *= dinv[row]
    scale_dinv_kernel<<<(N_NODES * 16) / 256, 256, 0, stream>>>(cnt, dinv, (f16x8*)hs);

    // ---- layer 0 aggregate + layer 1 GEMM (fused) -> hs1 ----
    gather_gemm_kernel<128><<<N_NODES / 16, 256, 0, stream>>>(
        cnt, esorted, dinv, (const f16x8*)hs, b0, Wt1, hs1);

    // ---- layer 1 aggregate + layer 2 GEMM (fused) -> hs2 ----
    gather_gemm_kernel<32><<<N_NODES / 16, 256, 0, stream>>>(
        cnt, esorted, dinv, (const f16x8*)hs1, b1, Wt2, hs2);

    // ---- layer 2 aggregate fused with log_softmax, writes d_out ----
    gather_lsm_kernel<<<(N_NODES * 4 + 255) / 256, 256, 0, stream>>>(
        cnt, esorted, dinv, (const f16x8*)hs2, b2, out);
}